// Round 18
// baseline (160.781 us; speedup 1.0000x reference)
//
#include <hip/hip_runtime.h>

#define NN 50000
#define NE 800000
#define DIN 256
#define DOUT 256
#define NSLICE 8
#define QPAD 32     // ints; 128B separation between per-bucket counters
#define DRANGE (NN / NSLICE)  // 6250 exact
#define SLOTS 32
#define OVFCAP 4096
#define PREP_BLKS 12756   // 12500 quant + 256 Wt
#define PART_BLKS 1024
#define EPB ((NE + PART_BLKS - 1) / PART_BLKS)  // 782 edges per partition block
#define BCAP 131072       // per-bucket capacity (expected ~100K)
#define SCHUNK 1024
#define MAXCH (BCAP / SCHUNK)  // 128

typedef __attribute__((ext_vector_type(8))) short short8;
typedef __attribute__((ext_vector_type(4))) float floatx4;

static __device__ __forceinline__ unsigned short f2bf(float f) {
    unsigned int u = __float_as_uint(f);
    unsigned int r = (u + 0x7fffu + ((u >> 16) & 1u)) >> 16;
    return (unsigned short)r;
}

static __device__ __forceinline__ void gload_lds16(const void* g, void* l) {
    __builtin_amdgcn_global_load_lds(
        (const __attribute__((address_space(1))) unsigned int*)g,
        (__attribute__((address_space(3))) unsigned int*)l, 16, 0, 0);
}

// ---------------- utility: zero ints ----------------
__global__ void zero_ints_kernel(int* __restrict__ p, int n) {
    int i = blockIdx.x * blockDim.x + threadIdx.x;
    if (i < n) p[i] = 0;
}

// ---- pass A (fused): quantize x -> int8, cast+transpose W, AND partition the
//      edge list into 8 packed per-XCD-range buckets (1x coalesced read,
//      sequential packed write; kills R17's 8x re-read + L2 slot churn).
__global__ __launch_bounds__(256) void work_kernel(const float* __restrict__ x,
                                                   const float* __restrict__ W,
                                                   unsigned int* __restrict__ xq,
                                                   float* __restrict__ sinv,
                                                   unsigned short* __restrict__ Wt,
                                                   const int* __restrict__ edge_src,
                                                   const int* __restrict__ edge_dst,
                                                   unsigned int* __restrict__ part,
                                                   int* __restrict__ gcur) {
    int bid = blockIdx.x;
    int tid = threadIdx.x;
    if (bid < 12500) {
        // quantize x -> int8 with per-row scale; wave per row, 4 rows/block
        int row = bid * 4 + (tid >> 6);
        int lane = tid & 63;
        float4 v = *(const float4*)(x + (size_t)row * DIN + lane * 4);
        float m = fmaxf(fmaxf(fabsf(v.x), fabsf(v.y)), fmaxf(fabsf(v.z), fabsf(v.w)));
#pragma unroll
        for (int d = 1; d < 64; d <<= 1) m = fmaxf(m, __shfl_xor(m, d));
        m = fmaxf(m, 1e-20f);
        float sc = 127.0f / m;
        int q0 = (int)rintf(v.x * sc);
        int q1 = (int)rintf(v.y * sc);
        int q2 = (int)rintf(v.z * sc);
        int q3 = (int)rintf(v.w * sc);
        unsigned int pack = (q0 & 255) | ((q1 & 255) << 8) | ((q2 & 255) << 16) | ((q3 & 255) << 24);
        xq[(size_t)row * 64 + lane] = pack;
        if (lane == 0) sinv[row] = m * (1.0f / 127.0f);
        return;
    }
    if (bid < PREP_BLKS) {
        int n = bid - 12500;
        Wt[(size_t)n * DIN + tid] = f2bf(W[(size_t)tid * DOUT + n]);
        return;
    }
    // ---- edge partition: this block owns edges [pb*EPB, pb*EPB+EPB) ----
    __shared__ int lcnt[8];
    __shared__ int lbase[8];
    int pb = bid - PREP_BLKS;
    int ebeg = pb * EPB;
    int eend = ebeg + EPB; if (eend > NE) eend = NE;
    for (int base = ebeg; base < eend; base += 256) {
        int e = base + tid;
        int q = -1, lrank = 0;
        unsigned int pack = 0;
        if (tid < 8) lcnt[tid] = 0;
        __syncthreads();
        if (e < eend) {
            int d = edge_dst[e];
            int s = edge_src[e];
            q = d / DRANGE;  // 0..7
            pack = ((unsigned int)(d - q * DRANGE) << 16) | (unsigned int)s;
            lrank = atomicAdd(&lcnt[q], 1);
        }
        __syncthreads();
        if (tid < 8) lbase[tid] = atomicAdd(&gcur[tid * QPAD], lcnt[tid]);
        __syncthreads();
        if (q >= 0) {
            int pos = lbase[q] + lrank;
            if (pos < BCAP) part[(size_t)q * BCAP + pos] = pack;
        }
        __syncthreads();  // protect lcnt re-zero next iter
    }
}

// ---- pass B: XCD-local slotted scatter from the packed per-bucket lists.
// XCD q's stream (~400KB) + its slot region (~400KB u16) both fit its 4MB L2:
// no churn, no re-read, all cnt/slot atomics XCD-local (R14/R16 machinery).
__global__ __launch_bounds__(256) void scatter2_kernel(const unsigned int* __restrict__ part,
                                                       const int* __restrict__ gcur,
                                                       int* __restrict__ qctr,
                                                       int* __restrict__ cnt,
                                                       unsigned short* __restrict__ slots,
                                                       int* __restrict__ ovf_n,
                                                       int* __restrict__ ovf_d,
                                                       int* __restrict__ ovf_s) {
    __shared__ int sh;
    int xcd;
    asm("s_getreg_b32 %0, hwreg(HW_REG_XCC_ID, 0, 32)" : "=s"(xcd));
    xcd &= 7;
    int tid = threadIdx.x;
    if (tid == 0) {
        int found = -1;
        for (int t = 0; t < NSLICE; t++) {
            int q = (xcd + t) & 7;
            int cq = gcur[q * QPAD]; if (cq > BCAP) cq = BCAP;
            int need = (cq + SCHUNK - 1) / SCHUNK;
            int c = atomicAdd(&qctr[q * QPAD], 1);
            if (c < need) { found = q * 256 + c; break; }
        }
        sh = found;
    }
    __syncthreads();
    int f = sh;
    if (f < 0) return;
    int q = f >> 8;
    int c = f & 255;
    int count = gcur[q * QPAD]; if (count > BCAP) count = BCAP;
    const unsigned int* pp = part + (size_t)q * BCAP;
    int base = c * SCHUNK;
    int dbase = q * DRANGE;
#pragma unroll
    for (int k = 0; k < SCHUNK / 256; k++) {
        int e = base + k * 256 + tid;
        if (e < count) {
            unsigned int p = pp[e];
            int d = dbase + (int)(p >> 16);
            int src = (int)(p & 0xffffu);
            int pos = atomicAdd(&cnt[d], 1);
            if (pos < SLOTS) {
                slots[(d << 5) + pos] = (unsigned short)src;
            } else {
                int oi = atomicAdd(ovf_n, 1);
                if (oi < OVFCAP) { ovf_d[oi] = d; ovf_s[oi] = src; }
            }
        }
    }
}

// ---------------- per-node mean of int8 rows -> xm (bf16) ----------------
// 1 node per wave, edge-split halves; slots are contiguous u16[32] per node.
__global__ __launch_bounds__(256) void mean_kernel(const unsigned int* __restrict__ xq,
                                                   const float* __restrict__ sinv,
                                                   const int* __restrict__ cnt,
                                                   const unsigned short* __restrict__ slots,
                                                   const int* __restrict__ ovf_n,
                                                   const int* __restrict__ ovf_d,
                                                   const int* __restrict__ ovf_s,
                                                   unsigned short* __restrict__ xm) {
    int node = blockIdx.x * 4 + (threadIdx.x >> 6);  // 12500*4 == NN exactly
    int lane = threadIdx.x & 63;
    int half = lane >> 5;   // 0: even slots, 1: odd slots
    int cg = lane & 31;     // col group: 8 int8 cols each
    int cv = cnt[node];
    int end = (cv < SLOTS) ? cv : SLOTS;
    const unsigned short* sp = slots + (node << 5);
    const unsigned int* xcol = xq + cg * 2;
    float a[8];
#pragma unroll
    for (int j = 0; j < 8; j++) a[j] = 0.f;
    int i = half;
    for (; i + 6 < end; i += 8) {
        int s0 = sp[i], s1 = sp[i + 2], s2 = sp[i + 4], s3 = sp[i + 6];
        float c0 = sinv[s0], c1 = sinv[s1], c2 = sinv[s2], c3 = sinv[s3];
        int2 q0 = *(const int2*)(xcol + (size_t)s0 * 64);
        int2 q1 = *(const int2*)(xcol + (size_t)s1 * 64);
        int2 q2 = *(const int2*)(xcol + (size_t)s2 * 64);
        int2 q3 = *(const int2*)(xcol + (size_t)s3 * 64);
#pragma unroll
        for (int j = 0; j < 4; j++) {
            int sh = 8 * j;
            a[j]     += c0 * (float)((signed char)(q0.x >> sh))
                      + c1 * (float)((signed char)(q1.x >> sh))
                      + c2 * (float)((signed char)(q2.x >> sh))
                      + c3 * (float)((signed char)(q3.x >> sh));
            a[4 + j] += c0 * (float)((signed char)(q0.y >> sh))
                      + c1 * (float)((signed char)(q1.y >> sh))
                      + c2 * (float)((signed char)(q2.y >> sh))
                      + c3 * (float)((signed char)(q3.y >> sh));
        }
    }
    for (; i < end; i += 2) {
        int s = sp[i];
        float c = sinv[s];
        int2 qv = *(const int2*)(xcol + (size_t)s * 64);
#pragma unroll
        for (int j = 0; j < 4; j++) {
            int sh = 8 * j;
            a[j]     += c * (float)((signed char)(qv.x >> sh));
            a[4 + j] += c * (float)((signed char)(qv.y >> sh));
        }
    }
    // overflow edges (deg > SLOTS): only half 0 processes them (no double count)
    if (cv > SLOTS && half == 0) {
        int n = *ovf_n;
        if (n > OVFCAP) n = OVFCAP;
        for (int k = 0; k < n; k++) {
            if (ovf_d[k] == node) {
                int s = ovf_s[k];
                float c = sinv[s];
                int2 qv = *(const int2*)(xcol + (size_t)s * 64);
#pragma unroll
                for (int j = 0; j < 4; j++) {
                    int sh = 8 * j;
                    a[j]     += c * (float)((signed char)(qv.x >> sh));
                    a[4 + j] += c * (float)((signed char)(qv.y >> sh));
                }
            }
        }
    }
    // combine halves
#pragma unroll
    for (int j = 0; j < 8; j++) a[j] += __shfl_xor(a[j], 32);
    float inv = (cv > 0) ? 1.0f / (float)cv : 0.f;
    if (half == 0) {
        short8 o;
#pragma unroll
        for (int j = 0; j < 8; j++) o[j] = (short)f2bf(a[j] * inv);
        *(short8*)(xm + (size_t)node * DIN + cg * 8) = o;
    }
}

// ---------------- bf16 MFMA GEMM: out = xm @ W + b (f32), deg==0 rows -> 0 ----
__global__ __launch_bounds__(256) void gemm_mfma_kernel(const unsigned short* __restrict__ xm,
                                                        const unsigned short* __restrict__ Wt,
                                                        const float* __restrict__ b,
                                                        const int* __restrict__ cnt,
                                                        float* __restrict__ out) {
    __shared__ unsigned short As[128 * 32];  // [row][k], 8 KB
    __shared__ unsigned short Bs[128 * 32];  // [col][k], 8 KB
    int tid = threadIdx.x;
    int bm = blockIdx.x >> 1;
    int bn = blockIdx.x & 1;
    int row0 = bm * 128, col0 = bn * 128;
    int wave = tid >> 6, lane = tid & 63;
    int wr = wave >> 1, wc = wave & 1;
    int l15 = lane & 15, kgrp = lane >> 4;

    floatx4 acc[4][4];
#pragma unroll
    for (int m = 0; m < 4; m++)
#pragma unroll
        for (int n = 0; n < 4; n++) acc[m][n] = (floatx4){0.f, 0.f, 0.f, 0.f};

    int srow = tid >> 2;
    int kchunk = (tid & 3) * 8;

    for (int kc = 0; kc < DIN; kc += 32) {
#pragma unroll
        for (int i = 0; i < 2; i++) {
            int row = i * 64 + srow;
            int ga_row = row0 + row; if (ga_row >= NN) ga_row = NN - 1;
            gload_lds16(xm + (size_t)ga_row * DIN + kc + kchunk,
                        (char*)As + i * 4096 + wave * 1024);
            gload_lds16(Wt + (size_t)(col0 + row) * DIN + kc + kchunk,
                        (char*)Bs + i * 4096 + wave * 1024);
        }
        __syncthreads();

        short8 af[4], bf[4];
#pragma unroll
        for (int m = 0; m < 4; m++)
            af[m] = *(const short8*)&As[(wr * 64 + m * 16 + l15) * 32 + kgrp * 8];
#pragma unroll
        for (int n = 0; n < 4; n++)
            bf[n] = *(const short8*)&Bs[(wc * 64 + n * 16 + l15) * 32 + kgrp * 8];
#pragma unroll
        for (int m = 0; m < 4; m++)
#pragma unroll
            for (int n = 0; n < 4; n++)
                acc[m][n] = __builtin_amdgcn_mfma_f32_16x16x32_bf16(af[m], bf[n], acc[m][n], 0, 0, 0);
        __syncthreads();
    }

    float bias[4];
#pragma unroll
    for (int n = 0; n < 4; n++) bias[n] = b[col0 + wc * 64 + n * 16 + l15];

#pragma unroll
    for (int m = 0; m < 4; m++) {
#pragma unroll
        for (int r = 0; r < 4; r++) {
            int row = row0 + wr * 64 + m * 16 + kgrp * 4 + r;
            if (row < NN) {
                int dg = cnt[row];
#pragma unroll
                for (int n = 0; n < 4; n++) {
                    int col = col0 + wc * 64 + n * 16 + l15;
                    out[(size_t)row * DOUT + col] = (dg > 0) ? acc[m][n][r] + bias[n] : 0.f;
                }
            }
        }
    }
}

extern "C" void kernel_launch(void* const* d_in, const int* in_sizes, int n_in,
                              void* d_out, int out_size, void* d_ws, size_t ws_size,
                              hipStream_t stream) {
    const float* x = (const float*)d_in[0];
    const float* W = (const float*)d_in[1];
    const float* b = (const float*)d_in[2];
    const int* esrc = (const int*)d_in[3];
    const int* edst = (const int*)d_in[4];
    float* out = (float*)d_out;

    char* ws = (char*)d_ws;
    size_t off = 0;
    unsigned int* xq = (unsigned int*)(ws + off); off += (size_t)NN * DIN;           // 12.8 MB int8
    unsigned short* xm = (unsigned short*)(ws + off); off += (size_t)NN * DIN * 2;   // 25.6 MB
    float* sinv = (float*)(ws + off); off += (size_t)NN * sizeof(float);             // 200 KB
    unsigned short* Wt = (unsigned short*)(ws + off); off += (size_t)DIN * DOUT * 2; // 128 KB
    unsigned short* slots = (unsigned short*)(ws + off); off += (size_t)NN * SLOTS * 2;  // 3.2 MB u16
    unsigned int* part = (unsigned int*)(ws + off); off += (size_t)NSLICE * BCAP * 4;    // 4.2 MB
    int* cnt = (int*)(ws + off); off += (size_t)NN * sizeof(int);
    int* gcur = (int*)(ws + off); off += (size_t)NSLICE * QPAD * sizeof(int);   // contiguous with cnt
    int* qctr2 = (int*)(ws + off); off += (size_t)NSLICE * QPAD * sizeof(int);  // contiguous
    int* ovf_n = (int*)(ws + off); off += 4 * sizeof(int);                      // contiguous
    int* ovf_d = (int*)(ws + off); off += OVFCAP * sizeof(int);
    int* ovf_s = (int*)(ws + off); off += OVFCAP * sizeof(int);

    const int nzero = NN + 2 * NSLICE * QPAD + 4;  // cnt + gcur + qctr2 + ovf_n
    zero_ints_kernel<<<(nzero + 255) / 256, 256, 0, stream>>>(cnt, nzero);
    work_kernel<<<PREP_BLKS + PART_BLKS, 256, 0, stream>>>(
        x, W, xq, sinv, Wt, esrc, edst, part, gcur);
    scatter2_kernel<<<NSLICE * 128, 256, 0, stream>>>(part, gcur, qctr2, cnt, slots,
                                                      ovf_n, ovf_d, ovf_s);
    mean_kernel<<<NN / 4, 256, 0, stream>>>(xq, sinv, cnt, slots, ovf_n, ovf_d, ovf_s, xm);
    gemm_mfma_kernel<<<391 * 2, 256, 0, stream>>>(xm, Wt, b, cnt, out);
}

// Round 19
// 103.951 us; speedup vs baseline: 1.5467x; 1.5467x over previous
//
#include <hip/hip_runtime.h>

#define NN 50000
#define NE 800000
#define DIN 256
#define DOUT 256
#define NR 8              // XCD-range buckets
#define RSZ 6250          // NN/NR
#define NSUB 196          // sub-buckets per range (32 dst each)
#define SUBCAP 1024       // per-sub-bucket capacity (avg ~510)
#define BCAP 131072       // per-range-bucket capacity (avg ~100K)
#define A1_BLKS 256
#define A1_EPB (NE / A1_BLKS)   // 3125
#define A2_BLKS 128             // 16 chunks per range-bucket
#define QP 8              // counter pad (ints, 32B)
#define OVFCAP 4096
#define WORK_GRID (A1_BLKS + 12500 + 256)

typedef __attribute__((ext_vector_type(8))) short short8;
typedef __attribute__((ext_vector_type(4))) float floatx4;

static __device__ __forceinline__ unsigned short f2bf(float f) {
    unsigned int u = __float_as_uint(f);
    unsigned int r = (u + 0x7fffu + ((u >> 16) & 1u)) >> 16;
    return (unsigned short)r;
}

static __device__ __forceinline__ void gload_lds16(const void* g, void* l) {
    __builtin_amdgcn_global_load_lds(
        (const __attribute__((address_space(1))) unsigned int*)g,
        (__attribute__((address_space(3))) unsigned int*)l, 16, 0, 0);
}

// ---------------- utility: zero ints ----------------
__global__ void zero_ints_kernel(int* __restrict__ p, int n) {
    int i = blockIdx.x * blockDim.x + threadIdx.x;
    if (i < n) p[i] = 0;
}

// ---- work: A1 edge partition (8-way, two-pass ranked, ONE flush per bucket
//      per block) runs concurrently with x-quant and Wt transpose. ----
__global__ __launch_bounds__(256) void work_kernel(const float* __restrict__ x,
                                                   const float* __restrict__ W,
                                                   unsigned int* __restrict__ xq,
                                                   float* __restrict__ sinv,
                                                   unsigned short* __restrict__ Wt,
                                                   const int* __restrict__ edge_src,
                                                   const int* __restrict__ edge_dst,
                                                   unsigned int* __restrict__ part,
                                                   int* __restrict__ gcur) {
    int bid = blockIdx.x;
    int tid = threadIdx.x;
    if (bid < A1_BLKS) {
        __shared__ int lcnt[NR];
        __shared__ int lbase[NR];
        int ebeg = bid * A1_EPB;
        int eend = ebeg + A1_EPB;  // NE divisible by 256
        if (tid < NR) lcnt[tid] = 0;
        __syncthreads();
        for (int e = ebeg + tid; e < eend; e += 256) {
            unsigned int d = (unsigned int)edge_dst[e];
            atomicAdd(&lcnt[d / RSZ], 1);
        }
        __syncthreads();
        if (tid < NR) {
            lbase[tid] = atomicAdd(&gcur[tid * QP], lcnt[tid]);
            lcnt[tid] = 0;
        }
        __syncthreads();
        for (int e = ebeg + tid; e < eend; e += 256) {
            unsigned int d = (unsigned int)edge_dst[e];
            unsigned int s = (unsigned int)edge_src[e];
            unsigned int q = d / RSZ;
            unsigned int dl = d - q * RSZ;
            int r = atomicAdd(&lcnt[q], 1);
            int pos = lbase[q] + r;
            if (pos < BCAP) part[(size_t)q * BCAP + pos] = (dl << 16) | s;
        }
        return;
    }
    if (bid < A1_BLKS + 12500) {
        // quantize x -> int8 with per-row scale; wave per row, 4 rows/block
        int row = (bid - A1_BLKS) * 4 + (tid >> 6);
        int lane = tid & 63;
        float4 v = *(const float4*)(x + (size_t)row * DIN + lane * 4);
        float m = fmaxf(fmaxf(fabsf(v.x), fabsf(v.y)), fmaxf(fabsf(v.z), fabsf(v.w)));
#pragma unroll
        for (int d = 1; d < 64; d <<= 1) m = fmaxf(m, __shfl_xor(m, d));
        m = fmaxf(m, 1e-20f);
        float sc = 127.0f / m;
        int q0 = (int)rintf(v.x * sc);
        int q1 = (int)rintf(v.y * sc);
        int q2 = (int)rintf(v.z * sc);
        int q3 = (int)rintf(v.w * sc);
        unsigned int pack = (q0 & 255) | ((q1 & 255) << 8) | ((q2 & 255) << 16) | ((q3 & 255) << 24);
        xq[(size_t)row * 64 + lane] = pack;
        if (lane == 0) sinv[row] = m * (1.0f / 127.0f);
        return;
    }
    {
        int n = bid - (A1_BLKS + 12500);
        Wt[(size_t)n * DIN + tid] = f2bf(W[(size_t)tid * DOUT + n]);
    }
}

// ---- A2: sub-partition each range-bucket into 196 sub-buckets (32 dst each).
//      16 chunk-blocks per bucket; two-pass LDS ranking; per-block flush;
//      writes land in ~128B contiguous runs. ----
__global__ __launch_bounds__(256) void subpart_kernel(const unsigned int* __restrict__ part,
                                                      const int* __restrict__ gcur,
                                                      int* __restrict__ scur,
                                                      unsigned int* __restrict__ sub) {
    __shared__ int lc[NSUB];
    __shared__ int lb[NSUB];
    int bid = blockIdx.x;
    int tid = threadIdx.x;
    int q = bid >> 4;
    int c = bid & 15;
    int count = gcur[q * QP]; if (count > BCAP) count = BCAP;
    int beg = (int)(((long long)c * count) >> 4);
    int end = (int)(((long long)(c + 1) * count) >> 4);
    const unsigned int* pp = part + (size_t)q * BCAP;
    if (tid < NSUB) lc[tid] = 0;
    __syncthreads();
    for (int i = beg + tid; i < end; i += 256) {
        unsigned int p = pp[i];
        atomicAdd(&lc[(p >> 16) >> 5], 1);
    }
    __syncthreads();
    if (tid < NSUB) {
        lb[tid] = atomicAdd(&scur[(q * NSUB + tid) * QP], lc[tid]);
        lc[tid] = 0;
    }
    __syncthreads();
    for (int i = beg + tid; i < end; i += 256) {
        unsigned int p = pp[i];
        int s = (p >> 16) >> 5;
        int r = atomicAdd(&lc[s], 1);
        int pos = lb[s] + r;
        if (pos < SUBCAP) sub[((size_t)(q * NSUB + s)) * SUBCAP + pos] = p;
    }
}

// ---- mean2: one block per sub-bucket (static). Slot packed edges into LDS
//      (LDS atomics -- global slot scatter eliminated), then proven
//      wave-per-node half-split int8 gather. Writes cnt non-atomically. ----
__global__ __launch_bounds__(256) void mean2_kernel(const unsigned int* __restrict__ xq,
                                                    const float* __restrict__ sinv,
                                                    const int* __restrict__ scur,
                                                    const unsigned int* __restrict__ sub,
                                                    int* __restrict__ ovf_n,
                                                    int* __restrict__ ovf_d,
                                                    int* __restrict__ ovf_s,
                                                    int* __restrict__ cnt,
                                                    unsigned short* __restrict__ xm) {
    __shared__ unsigned short slt[32 * 64];  // 4 KB
    __shared__ int lcn[32];
    int bid = blockIdx.x;
    int tid = threadIdx.x;
    int q = bid / NSUB;
    int s = bid - q * NSUB;
    int csub = scur[(q * NSUB + s) * QP]; if (csub > SUBCAP) csub = SUBCAP;
    int n0 = q * RSZ + s * 32;
    int nnodes = RSZ - s * 32; if (nnodes > 32) nnodes = 32;
    const unsigned int* sp = sub + ((size_t)(q * NSUB + s)) * SUBCAP;

    if (tid < 32) lcn[tid] = 0;
    __syncthreads();
    for (int i = tid; i < csub; i += 256) {
        unsigned int p = sp[i];
        int dl = (int)(p >> 16);
        int n5 = dl & 31;
        int pos = atomicAdd(&lcn[n5], 1);
        if (pos < 64) slt[n5 * 64 + pos] = (unsigned short)(p & 0xffffu);
        else {
            int oi = atomicAdd(ovf_n, 1);
            if (oi < OVFCAP) { ovf_d[oi] = q * RSZ + dl; ovf_s[oi] = (int)(p & 0xffffu); }
        }
    }
    __syncthreads();

    int wave = tid >> 6, lane = tid & 63;
    int half = lane >> 5;
    int cg = lane & 31;
    const unsigned int* xcol = xq + cg * 2;
    for (int w = 0; w < 8; w++) {
        int n5 = wave * 8 + w;
        if (n5 >= nnodes) break;
        int node = n0 + n5;
        int cv = lcn[n5];
        int end = (cv < 64) ? cv : 64;
        const unsigned short* sl = &slt[n5 * 64];
        float a[8];
#pragma unroll
        for (int j = 0; j < 8; j++) a[j] = 0.f;
        int i = half;
        for (; i + 6 < end; i += 8) {
            int s0 = sl[i], s1 = sl[i + 2], s2 = sl[i + 4], s3 = sl[i + 6];
            float c0 = sinv[s0], c1 = sinv[s1], c2 = sinv[s2], c3 = sinv[s3];
            int2 q0 = *(const int2*)(xcol + (size_t)s0 * 64);
            int2 q1 = *(const int2*)(xcol + (size_t)s1 * 64);
            int2 q2 = *(const int2*)(xcol + (size_t)s2 * 64);
            int2 q3 = *(const int2*)(xcol + (size_t)s3 * 64);
#pragma unroll
            for (int j = 0; j < 4; j++) {
                int sh = 8 * j;
                a[j]     += c0 * (float)((signed char)(q0.x >> sh))
                          + c1 * (float)((signed char)(q1.x >> sh))
                          + c2 * (float)((signed char)(q2.x >> sh))
                          + c3 * (float)((signed char)(q3.x >> sh));
                a[4 + j] += c0 * (float)((signed char)(q0.y >> sh))
                          + c1 * (float)((signed char)(q1.y >> sh))
                          + c2 * (float)((signed char)(q2.y >> sh))
                          + c3 * (float)((signed char)(q3.y >> sh));
            }
        }
        for (; i < end; i += 2) {
            int sv = sl[i];
            float c = sinv[sv];
            int2 qv = *(const int2*)(xcol + (size_t)sv * 64);
#pragma unroll
            for (int j = 0; j < 4; j++) {
                int sh = 8 * j;
                a[j]     += c * (float)((signed char)(qv.x >> sh));
                a[4 + j] += c * (float)((signed char)(qv.y >> sh));
            }
        }
        if (cv > 64 && half == 0) {
            int n = *ovf_n;
            if (n > OVFCAP) n = OVFCAP;
            for (int k = 0; k < n; k++) {
                if (ovf_d[k] == node) {
                    int sv = ovf_s[k];
                    float c = sinv[sv];
                    int2 qv = *(const int2*)(xcol + (size_t)sv * 64);
#pragma unroll
                    for (int j = 0; j < 4; j++) {
                        int sh = 8 * j;
                        a[j]     += c * (float)((signed char)(qv.x >> sh));
                        a[4 + j] += c * (float)((signed char)(qv.y >> sh));
                    }
                }
            }
        }
#pragma unroll
        for (int j = 0; j < 8; j++) a[j] += __shfl_xor(a[j], 32);
        float inv = (cv > 0) ? 1.0f / (float)cv : 0.f;
        if (half == 0) {
            short8 o;
#pragma unroll
            for (int j = 0; j < 8; j++) o[j] = (short)f2bf(a[j] * inv);
            *(short8*)(xm + (size_t)node * DIN + cg * 8) = o;
        }
        if (lane == 0) cnt[node] = cv;
    }
}

// ---------------- bf16 MFMA GEMM: out = xm @ W + b (f32), deg==0 rows -> 0 ----
__global__ __launch_bounds__(256) void gemm_mfma_kernel(const unsigned short* __restrict__ xm,
                                                        const unsigned short* __restrict__ Wt,
                                                        const float* __restrict__ b,
                                                        const int* __restrict__ cnt,
                                                        float* __restrict__ out) {
    __shared__ unsigned short As[128 * 32];  // [row][k], 8 KB
    __shared__ unsigned short Bs[128 * 32];  // [col][k], 8 KB
    int tid = threadIdx.x;
    int bm = blockIdx.x >> 1;
    int bn = blockIdx.x & 1;
    int row0 = bm * 128, col0 = bn * 128;
    int wave = tid >> 6, lane = tid & 63;
    int wr = wave >> 1, wc = wave & 1;
    int l15 = lane & 15, kgrp = lane >> 4;

    floatx4 acc[4][4];
#pragma unroll
    for (int m = 0; m < 4; m++)
#pragma unroll
        for (int n = 0; n < 4; n++) acc[m][n] = (floatx4){0.f, 0.f, 0.f, 0.f};

    int srow = tid >> 2;
    int kchunk = (tid & 3) * 8;

    for (int kc = 0; kc < DIN; kc += 32) {
#pragma unroll
        for (int i = 0; i < 2; i++) {
            int row = i * 64 + srow;
            int ga_row = row0 + row; if (ga_row >= NN) ga_row = NN - 1;
            gload_lds16(xm + (size_t)ga_row * DIN + kc + kchunk,
                        (char*)As + i * 4096 + wave * 1024);
            gload_lds16(Wt + (size_t)(col0 + row) * DIN + kc + kchunk,
                        (char*)Bs + i * 4096 + wave * 1024);
        }
        __syncthreads();

        short8 af[4], bf[4];
#pragma unroll
        for (int m = 0; m < 4; m++)
            af[m] = *(const short8*)&As[(wr * 64 + m * 16 + l15) * 32 + kgrp * 8];
#pragma unroll
        for (int n = 0; n < 4; n++)
            bf[n] = *(const short8*)&Bs[(wc * 64 + n * 16 + l15) * 32 + kgrp * 8];
#pragma unroll
        for (int m = 0; m < 4; m++)
#pragma unroll
            for (int n = 0; n < 4; n++)
                acc[m][n] = __builtin_amdgcn_mfma_f32_16x16x32_bf16(af[m], bf[n], acc[m][n], 0, 0, 0);
        __syncthreads();
    }

    float bias[4];
#pragma unroll
    for (int n = 0; n < 4; n++) bias[n] = b[col0 + wc * 64 + n * 16 + l15];

#pragma unroll
    for (int m = 0; m < 4; m++) {
#pragma unroll
        for (int r = 0; r < 4; r++) {
            int row = row0 + wr * 64 + m * 16 + kgrp * 4 + r;
            if (row < NN) {
                int dg = cnt[row];
#pragma unroll
                for (int n = 0; n < 4; n++) {
                    int col = col0 + wc * 64 + n * 16 + l15;
                    out[(size_t)row * DOUT + col] = (dg > 0) ? acc[m][n][r] + bias[n] : 0.f;
                }
            }
        }
    }
}

extern "C" void kernel_launch(void* const* d_in, const int* in_sizes, int n_in,
                              void* d_out, int out_size, void* d_ws, size_t ws_size,
                              hipStream_t stream) {
    const float* x = (const float*)d_in[0];
    const float* W = (const float*)d_in[1];
    const float* b = (const float*)d_in[2];
    const int* esrc = (const int*)d_in[3];
    const int* edst = (const int*)d_in[4];
    float* out = (float*)d_out;

    char* ws = (char*)d_ws;
    size_t off = 0;
    unsigned int* xq = (unsigned int*)(ws + off); off += (size_t)NN * DIN;           // 12.8 MB
    unsigned short* xm = (unsigned short*)(ws + off); off += (size_t)NN * DIN * 2;   // 25.6 MB
    float* sinv = (float*)(ws + off); off += (size_t)NN * sizeof(float);             // 200 KB
    unsigned short* Wt = (unsigned short*)(ws + off); off += (size_t)DIN * DOUT * 2; // 128 KB
    unsigned int* part = (unsigned int*)(ws + off); off += (size_t)NR * BCAP * 4;    // 4.2 MB
    unsigned int* sub = (unsigned int*)(ws + off); off += (size_t)NR * NSUB * SUBCAP * 4;  // 6.4 MB
    int* cnt = (int*)(ws + off); off += (size_t)NN * sizeof(int);                    // contiguous zero region:
    int* gcur = (int*)(ws + off); off += (size_t)NR * QP * sizeof(int);
    int* scur = (int*)(ws + off); off += (size_t)NR * NSUB * QP * sizeof(int);
    int* ovf_n = (int*)(ws + off); off += 4 * sizeof(int);
    int* ovf_d = (int*)(ws + off); off += OVFCAP * sizeof(int);
    int* ovf_s = (int*)(ws + off); off += OVFCAP * sizeof(int);

    const int nzero = NN + NR * QP + NR * NSUB * QP + 4;  // cnt + gcur + scur + ovf_n
    zero_ints_kernel<<<(nzero + 255) / 256, 256, 0, stream>>>(cnt, nzero);
    work_kernel<<<WORK_GRID, 256, 0, stream>>>(x, W, xq, sinv, Wt, esrc, edst, part, gcur);
    subpart_kernel<<<A2_BLKS, 256, 0, stream>>>(part, gcur, scur, sub);
    mean2_kernel<<<NR * NSUB, 256, 0, stream>>>(xq, sinv, scur, sub, ovf_n, ovf_d, ovf_s, cnt, xm);
    gemm_mfma_kernel<<<391 * 2, 256, 0, stream>>>(xm, Wt, b, cnt, out);
}

// Round 20
// 101.260 us; speedup vs baseline: 1.5878x; 1.0266x over previous
//
#include <hip/hip_runtime.h>

#define NN 50000
#define NE 800000
#define DIN 256
#define DOUT 256
#define NR 8              // XCD-range buckets
#define RSZ 6250          // NN/NR
#define NSUB 196          // sub-buckets per range (32 dst each)
#define SUBCAP 1024       // per-sub-bucket capacity (avg ~510)
#define BCAP 131072       // per-range-bucket capacity (avg ~100K)
#define A1_BLKS 256
#define A1_EPB (NE / A1_BLKS)   // 3125
#define A2_BLKS 128             // 16 chunks per range-bucket
#define QP 8              // counter pad (ints, 32B)
#define OVFCAP 4096
#define WORK_GRID (A1_BLKS + 12500 + 256)

typedef __attribute__((ext_vector_type(8))) short short8;
typedef __attribute__((ext_vector_type(4))) float floatx4;

static __device__ __forceinline__ unsigned short f2bf(float f) {
    unsigned int u = __float_as_uint(f);
    unsigned int r = (u + 0x7fffu + ((u >> 16) & 1u)) >> 16;
    return (unsigned short)r;
}

static __device__ __forceinline__ void gload_lds16(const void* g, void* l) {
    __builtin_amdgcn_global_load_lds(
        (const __attribute__((address_space(1))) unsigned int*)g,
        (__attribute__((address_space(3))) unsigned int*)l, 16, 0, 0);
}

// ---------------- utility: zero ints ----------------
__global__ void zero_ints_kernel(int* __restrict__ p, int n) {
    int i = blockIdx.x * blockDim.x + threadIdx.x;
    if (i < n) p[i] = 0;
}

// ---- work: A1 edge partition (8-way, two-pass ranked, ONE flush per bucket
//      per block) runs concurrently with x-quant and Wt transpose. ----
__global__ __launch_bounds__(256) void work_kernel(const float* __restrict__ x,
                                                   const float* __restrict__ W,
                                                   unsigned int* __restrict__ xq,
                                                   float* __restrict__ sinv,
                                                   unsigned short* __restrict__ Wt,
                                                   const int* __restrict__ edge_src,
                                                   const int* __restrict__ edge_dst,
                                                   unsigned int* __restrict__ part,
                                                   int* __restrict__ gcur) {
    int bid = blockIdx.x;
    int tid = threadIdx.x;
    if (bid < A1_BLKS) {
        __shared__ int lcnt[NR];
        __shared__ int lbase[NR];
        int ebeg = bid * A1_EPB;
        int eend = ebeg + A1_EPB;  // NE divisible by 256
        if (tid < NR) lcnt[tid] = 0;
        __syncthreads();
        for (int e = ebeg + tid; e < eend; e += 256) {
            unsigned int d = (unsigned int)edge_dst[e];
            atomicAdd(&lcnt[d / RSZ], 1);
        }
        __syncthreads();
        if (tid < NR) {
            lbase[tid] = atomicAdd(&gcur[tid * QP], lcnt[tid]);
            lcnt[tid] = 0;
        }
        __syncthreads();
        for (int e = ebeg + tid; e < eend; e += 256) {
            unsigned int d = (unsigned int)edge_dst[e];
            unsigned int s = (unsigned int)edge_src[e];
            unsigned int q = d / RSZ;
            unsigned int dl = d - q * RSZ;
            int r = atomicAdd(&lcnt[q], 1);
            int pos = lbase[q] + r;
            if (pos < BCAP) part[(size_t)q * BCAP + pos] = (dl << 16) | s;
        }
        return;
    }
    if (bid < A1_BLKS + 12500) {
        // quantize x -> int8 with per-row scale; wave per row, 4 rows/block
        int row = (bid - A1_BLKS) * 4 + (tid >> 6);
        int lane = tid & 63;
        float4 v = *(const float4*)(x + (size_t)row * DIN + lane * 4);
        float m = fmaxf(fmaxf(fabsf(v.x), fabsf(v.y)), fmaxf(fabsf(v.z), fabsf(v.w)));
#pragma unroll
        for (int d = 1; d < 64; d <<= 1) m = fmaxf(m, __shfl_xor(m, d));
        m = fmaxf(m, 1e-20f);
        float sc = 127.0f / m;
        int q0 = (int)rintf(v.x * sc);
        int q1 = (int)rintf(v.y * sc);
        int q2 = (int)rintf(v.z * sc);
        int q3 = (int)rintf(v.w * sc);
        unsigned int pack = (q0 & 255) | ((q1 & 255) << 8) | ((q2 & 255) << 16) | ((q3 & 255) << 24);
        xq[(size_t)row * 64 + lane] = pack;
        if (lane == 0) sinv[row] = m * (1.0f / 127.0f);
        return;
    }
    {
        int n = bid - (A1_BLKS + 12500);
        Wt[(size_t)n * DIN + tid] = f2bf(W[(size_t)tid * DOUT + n]);
    }
}

// ---- A2: sub-partition each range-bucket into 196 sub-buckets (32 dst each).
//      16 chunk-blocks per bucket; two-pass LDS ranking; per-block flush;
//      writes land in ~128B contiguous runs. ----
__global__ __launch_bounds__(256) void subpart_kernel(const unsigned int* __restrict__ part,
                                                      const int* __restrict__ gcur,
                                                      int* __restrict__ scur,
                                                      unsigned int* __restrict__ sub) {
    __shared__ int lc[NSUB];
    __shared__ int lb[NSUB];
    int bid = blockIdx.x;
    int tid = threadIdx.x;
    int q = bid >> 4;
    int c = bid & 15;
    int count = gcur[q * QP]; if (count > BCAP) count = BCAP;
    int beg = (int)(((long long)c * count) >> 4);
    int end = (int)(((long long)(c + 1) * count) >> 4);
    const unsigned int* pp = part + (size_t)q * BCAP;
    if (tid < NSUB) lc[tid] = 0;
    __syncthreads();
    for (int i = beg + tid; i < end; i += 256) {
        unsigned int p = pp[i];
        atomicAdd(&lc[(p >> 16) >> 5], 1);
    }
    __syncthreads();
    if (tid < NSUB) {
        lb[tid] = atomicAdd(&scur[(q * NSUB + tid) * QP], lc[tid]);
        lc[tid] = 0;
    }
    __syncthreads();
    for (int i = beg + tid; i < end; i += 256) {
        unsigned int p = pp[i];
        int s = (p >> 16) >> 5;
        int r = atomicAdd(&lc[s], 1);
        int pos = lb[s] + r;
        if (pos < SUBCAP) sub[((size_t)(q * NSUB + s)) * SUBCAP + pos] = p;
    }
}

// ---- mean2: TWO blocks per sub-bucket (grid 3136, ~12/CU: fixes R19's 37%
//      occupancy). Each block owns 16 of the 32 nodes; scans the sub-bucket
//      list, slots only its half into LDS (atomics in LDS), then the proven
//      wave-per-node half-split int8 gather. 4 waves x 4 nodes in phase 2.
__global__ __launch_bounds__(256) void mean2_kernel(const unsigned int* __restrict__ xq,
                                                    const float* __restrict__ sinv,
                                                    const int* __restrict__ scur,
                                                    const unsigned int* __restrict__ sub,
                                                    int* __restrict__ ovf_n,
                                                    int* __restrict__ ovf_d,
                                                    int* __restrict__ ovf_s,
                                                    int* __restrict__ cnt,
                                                    unsigned short* __restrict__ xm) {
    __shared__ unsigned short slt[16 * 64];  // 2 KB
    __shared__ int lcn[16];
    int bid = blockIdx.x;
    int tid = threadIdx.x;
    int sb = bid >> 1;            // sub-bucket id 0..1567
    int hb = bid & 1;             // which half of the 32 nodes
    int q = sb / NSUB;
    int s = sb - q * NSUB;
    int csub = scur[(q * NSUB + s) * QP]; if (csub > SUBCAP) csub = SUBCAP;
    int n0 = q * RSZ + s * 32 + hb * 16;
    int nrem = RSZ - (s * 32 + hb * 16);
    int nnodes = (nrem < 16) ? ((nrem < 0) ? 0 : nrem) : 16;
    const unsigned int* sp = sub + ((size_t)(q * NSUB + s)) * SUBCAP;

    if (tid < 16) lcn[tid] = 0;
    __syncthreads();
    for (int i = tid; i < csub; i += 256) {
        unsigned int p = sp[i];
        int dl = (int)(p >> 16);
        int h = (dl >> 4) & 1;
        if (h != hb) continue;
        int n4 = dl & 15;
        int pos = atomicAdd(&lcn[n4], 1);
        if (pos < 64) slt[n4 * 64 + pos] = (unsigned short)(p & 0xffffu);
        else {
            int oi = atomicAdd(ovf_n, 1);
            if (oi < OVFCAP) { ovf_d[oi] = q * RSZ + dl; ovf_s[oi] = (int)(p & 0xffffu); }
        }
    }
    __syncthreads();

    int wave = tid >> 6, lane = tid & 63;
    int half = lane >> 5;
    int cg = lane & 31;
    const unsigned int* xcol = xq + cg * 2;
    for (int w = 0; w < 4; w++) {
        int n4 = wave * 4 + w;
        if (n4 >= nnodes) break;
        int node = n0 + n4;
        int cv = lcn[n4];
        int end = (cv < 64) ? cv : 64;
        const unsigned short* sl = &slt[n4 * 64];
        float a[8];
#pragma unroll
        for (int j = 0; j < 8; j++) a[j] = 0.f;
        int i = half;
        for (; i + 6 < end; i += 8) {
            int s0 = sl[i], s1 = sl[i + 2], s2 = sl[i + 4], s3 = sl[i + 6];
            float c0 = sinv[s0], c1 = sinv[s1], c2 = sinv[s2], c3 = sinv[s3];
            int2 q0 = *(const int2*)(xcol + (size_t)s0 * 64);
            int2 q1 = *(const int2*)(xcol + (size_t)s1 * 64);
            int2 q2 = *(const int2*)(xcol + (size_t)s2 * 64);
            int2 q3 = *(const int2*)(xcol + (size_t)s3 * 64);
#pragma unroll
            for (int j = 0; j < 4; j++) {
                int sh = 8 * j;
                a[j]     += c0 * (float)((signed char)(q0.x >> sh))
                          + c1 * (float)((signed char)(q1.x >> sh))
                          + c2 * (float)((signed char)(q2.x >> sh))
                          + c3 * (float)((signed char)(q3.x >> sh));
                a[4 + j] += c0 * (float)((signed char)(q0.y >> sh))
                          + c1 * (float)((signed char)(q1.y >> sh))
                          + c2 * (float)((signed char)(q2.y >> sh))
                          + c3 * (float)((signed char)(q3.y >> sh));
            }
        }
        for (; i < end; i += 2) {
            int sv = sl[i];
            float c = sinv[sv];
            int2 qv = *(const int2*)(xcol + (size_t)sv * 64);
#pragma unroll
            for (int j = 0; j < 4; j++) {
                int sh = 8 * j;
                a[j]     += c * (float)((signed char)(qv.x >> sh));
                a[4 + j] += c * (float)((signed char)(qv.y >> sh));
            }
        }
        if (cv > 64 && half == 0) {
            int n = *ovf_n;
            if (n > OVFCAP) n = OVFCAP;
            for (int k = 0; k < n; k++) {
                if (ovf_d[k] == node) {
                    int sv = ovf_s[k];
                    float c = sinv[sv];
                    int2 qv = *(const int2*)(xcol + (size_t)sv * 64);
#pragma unroll
                    for (int j = 0; j < 4; j++) {
                        int sh = 8 * j;
                        a[j]     += c * (float)((signed char)(qv.x >> sh));
                        a[4 + j] += c * (float)((signed char)(qv.y >> sh));
                    }
                }
            }
        }
#pragma unroll
        for (int j = 0; j < 8; j++) a[j] += __shfl_xor(a[j], 32);
        float inv = (cv > 0) ? 1.0f / (float)cv : 0.f;
        if (half == 0) {
            short8 o;
#pragma unroll
            for (int j = 0; j < 8; j++) o[j] = (short)f2bf(a[j] * inv);
            *(short8*)(xm + (size_t)node * DIN + cg * 8) = o;
        }
        if (lane == 0) cnt[node] = cv;
    }
}

// ---------------- bf16 MFMA GEMM: out = xm @ W + b (f32), deg==0 rows -> 0 ----
__global__ __launch_bounds__(256) void gemm_mfma_kernel(const unsigned short* __restrict__ xm,
                                                        const unsigned short* __restrict__ Wt,
                                                        const float* __restrict__ b,
                                                        const int* __restrict__ cnt,
                                                        float* __restrict__ out) {
    __shared__ unsigned short As[128 * 32];  // [row][k], 8 KB
    __shared__ unsigned short Bs[128 * 32];  // [col][k], 8 KB
    int tid = threadIdx.x;
    int bm = blockIdx.x >> 1;
    int bn = blockIdx.x & 1;
    int row0 = bm * 128, col0 = bn * 128;
    int wave = tid >> 6, lane = tid & 63;
    int wr = wave >> 1, wc = wave & 1;
    int l15 = lane & 15, kgrp = lane >> 4;

    floatx4 acc[4][4];
#pragma unroll
    for (int m = 0; m < 4; m++)
#pragma unroll
        for (int n = 0; n < 4; n++) acc[m][n] = (floatx4){0.f, 0.f, 0.f, 0.f};

    int srow = tid >> 2;
    int kchunk = (tid & 3) * 8;

    for (int kc = 0; kc < DIN; kc += 32) {
#pragma unroll
        for (int i = 0; i < 2; i++) {
            int row = i * 64 + srow;
            int ga_row = row0 + row; if (ga_row >= NN) ga_row = NN - 1;
            gload_lds16(xm + (size_t)ga_row * DIN + kc + kchunk,
                        (char*)As + i * 4096 + wave * 1024);
            gload_lds16(Wt + (size_t)(col0 + row) * DIN + kc + kchunk,
                        (char*)Bs + i * 4096 + wave * 1024);
        }
        __syncthreads();

        short8 af[4], bf[4];
#pragma unroll
        for (int m = 0; m < 4; m++)
            af[m] = *(const short8*)&As[(wr * 64 + m * 16 + l15) * 32 + kgrp * 8];
#pragma unroll
        for (int n = 0; n < 4; n++)
            bf[n] = *(const short8*)&Bs[(wc * 64 + n * 16 + l15) * 32 + kgrp * 8];
#pragma unroll
        for (int m = 0; m < 4; m++)
#pragma unroll
            for (int n = 0; n < 4; n++)
                acc[m][n] = __builtin_amdgcn_mfma_f32_16x16x32_bf16(af[m], bf[n], acc[m][n], 0, 0, 0);
        __syncthreads();
    }

    float bias[4];
#pragma unroll
    for (int n = 0; n < 4; n++) bias[n] = b[col0 + wc * 64 + n * 16 + l15];

#pragma unroll
    for (int m = 0; m < 4; m++) {
#pragma unroll
        for (int r = 0; r < 4; r++) {
            int row = row0 + wr * 64 + m * 16 + kgrp * 4 + r;
            if (row < NN) {
                int dg = cnt[row];
#pragma unroll
                for (int n = 0; n < 4; n++) {
                    int col = col0 + wc * 64 + n * 16 + l15;
                    out[(size_t)row * DOUT + col] = (dg > 0) ? acc[m][n][r] + bias[n] : 0.f;
                }
            }
        }
    }
}

extern "C" void kernel_launch(void* const* d_in, const int* in_sizes, int n_in,
                              void* d_out, int out_size, void* d_ws, size_t ws_size,
                              hipStream_t stream) {
    const float* x = (const float*)d_in[0];
    const float* W = (const float*)d_in[1];
    const float* b = (const float*)d_in[2];
    const int* esrc = (const int*)d_in[3];
    const int* edst = (const int*)d_in[4];
    float* out = (float*)d_out;

    char* ws = (char*)d_ws;
    size_t off = 0;
    unsigned int* xq = (unsigned int*)(ws + off); off += (size_t)NN * DIN;           // 12.8 MB
    unsigned short* xm = (unsigned short*)(ws + off); off += (size_t)NN * DIN * 2;   // 25.6 MB
    float* sinv = (float*)(ws + off); off += (size_t)NN * sizeof(float);             // 200 KB
    unsigned short* Wt = (unsigned short*)(ws + off); off += (size_t)DIN * DOUT * 2; // 128 KB
    unsigned int* part = (unsigned int*)(ws + off); off += (size_t)NR * BCAP * 4;    // 4.2 MB
    unsigned int* sub = (unsigned int*)(ws + off); off += (size_t)NR * NSUB * SUBCAP * 4;  // 6.4 MB
    int* cnt = (int*)(ws + off); off += (size_t)NN * sizeof(int);                    // contiguous zero region:
    int* gcur = (int*)(ws + off); off += (size_t)NR * QP * sizeof(int);
    int* scur = (int*)(ws + off); off += (size_t)NR * NSUB * QP * sizeof(int);
    int* ovf_n = (int*)(ws + off); off += 4 * sizeof(int);
    int* ovf_d = (int*)(ws + off); off += OVFCAP * sizeof(int);
    int* ovf_s = (int*)(ws + off); off += OVFCAP * sizeof(int);

    const int nzero = NN + NR * QP + NR * NSUB * QP + 4;  // cnt + gcur + scur + ovf_n
    zero_ints_kernel<<<(nzero + 255) / 256, 256, 0, stream>>>(cnt, nzero);
    work_kernel<<<WORK_GRID, 256, 0, stream>>>(x, W, xq, sinv, Wt, esrc, edst, part, gcur);
    subpart_kernel<<<A2_BLKS, 256, 0, stream>>>(part, gcur, scur, sub);
    mean2_kernel<<<NR * NSUB * 2, 256, 0, stream>>>(xq, sinv, scur, sub, ovf_n, ovf_d, ovf_s, cnt, xm);
    gemm_mfma_kernel<<<391 * 2, 256, 0, stream>>>(xm, Wt, b, cnt, out);
}